// Round 5
// baseline (4995.781 us; speedup 1.0000x reference)
//
#include <hip/hip_runtime.h>

#define NN 50000
#define NE 800000
#define INF 7
#define GD 16
#define LAT 64
#define HID 128

typedef unsigned short u16;

__device__ __forceinline__ float bf2f(u16 u) {
  union { unsigned int i; float f; } v; v.i = ((unsigned int)u) << 16; return v.f;
}
__device__ __forceinline__ u16 f2bf(float f) {
  union { float f; unsigned int i; } v; v.f = f;
  unsigned int x = v.i;
  return (u16)((x + 0x7fffu + ((x >> 16) & 1u)) >> 16);
}
// jax.nn.gelu default: approximate=True (tanh form)
__device__ __forceinline__ float gelu(float x) {
  float z = 0.7978845608028654f * (x + 0.044715f * x * x * x);
  float e = __expf(2.0f * z);
  float th = 1.0f - 2.0f / (e + 1.0f);
  return 0.5f * x * (1.0f + th);
}

__global__ void embed_kernel(const float* __restrict__ nodes, const float* __restrict__ w,
                             const float* __restrict__ b, float* __restrict__ h) {
  int gid = blockIdx.x * blockDim.x + threadIdx.x;
  if (gid >= NN * LAT) return;
  int n = gid >> 6, j = gid & 63;
  float acc = b[j];
#pragma unroll
  for (int k = 0; k < INF; ++k)
    acc = fmaf(nodes[n * INF + k], w[k * LAT + j], acc);
  h[gid] = acc;
}

__global__ void zero_kernel(float4* __restrict__ p, int n4) {
  int i = blockIdx.x * blockDim.x + threadIdx.x;
  if (i < n4) p[i] = make_float4(0.f, 0.f, 0.f, 0.f);
}

// Edge MLP: in = [e_prev?, s, r, g] (KIN=144 for t=0 else 208)
// LDS = ins + hid only (21.8 KB max). W1/W2 read fp32 from global (L1/L2 broadcast).
template <int KIN>
__launch_bounds__(128)
__global__ void edge_kernel(const float* __restrict__ h,
                            const u16* e_prev, u16* e_out,
                            float* __restrict__ recvbuf,
                            const int* __restrict__ snd, const int* __restrict__ rcv,
                            const float* __restrict__ gv,
                            const float* __restrict__ w1, const float* __restrict__ b1,
                            const float* __restrict__ w2, const float* __restrict__ b2) {
  __shared__ __align__(16) float ins[16][KIN];
  __shared__ __align__(16) float hid[16][HID + 4];
  const int tid = threadIdx.x;

  const int j1 = (tid & 31) * 4;  // phase-1 column group (128 cols)
  const int e1 = (tid >> 5) * 4;  // phase-1 rows (4 edges)
  const int j2 = (tid & 15) * 4;  // phase-2 column group (64 cols)
  const int e2 = (tid >> 4) * 2;  // phase-2 rows (2 edges)
  float bb1[4], bb2[4];
#pragma unroll
  for (int c = 0; c < 4; ++c) { bb1[c] = b1[j1 + c]; bb2[c] = b2[j2 + c]; }

  for (int tile = blockIdx.x; tile < NE / 16; tile += gridDim.x) {
    const int ebase = tile * 16;
    for (int e = 0; e < 16; ++e) {
      const int eg = ebase + e;
      const int s = snd[eg], r = rcv[eg];
      if (KIN == 144) {
        for (int c = tid; c < 144; c += 128) {
          float v;
          if (c < 64)       v = h[s * 64 + c];
          else if (c < 128) v = h[r * 64 + c - 64];
          else              v = gv[c - 128];
          ins[e][c] = v;
        }
      } else {
        for (int c = tid; c < 208; c += 128) {
          float v;
          if (c < 64)       v = bf2f(e_prev[(long)eg * 64 + c]);
          else if (c < 128) v = h[s * 64 + c - 64];
          else if (c < 192) v = h[r * 64 + c - 128];
          else              v = gv[c - 192];
          ins[e][c] = v;
        }
      }
    }
    __syncthreads();
    // phase 1: hidden = gelu(in @ W1 + b1)
    {
      float acc[4][4];
#pragma unroll
      for (int r = 0; r < 4; ++r)
#pragma unroll
        for (int c = 0; c < 4; ++c) acc[r][c] = bb1[c];
      for (int k = 0; k < KIN; ++k) {
        float4 wp = *(const float4*)&w1[k * HID + j1];
#pragma unroll
        for (int r = 0; r < 4; ++r) {
          float iv = ins[e1 + r][k];
          acc[r][0] = fmaf(iv, wp.x, acc[r][0]);
          acc[r][1] = fmaf(iv, wp.y, acc[r][1]);
          acc[r][2] = fmaf(iv, wp.z, acc[r][2]);
          acc[r][3] = fmaf(iv, wp.w, acc[r][3]);
        }
      }
#pragma unroll
      for (int r = 0; r < 4; ++r) {
        float4 o;
        o.x = gelu(acc[r][0]); o.y = gelu(acc[r][1]);
        o.z = gelu(acc[r][2]); o.w = gelu(acc[r][3]);
        *(float4*)&hid[e1 + r][j1] = o;
      }
    }
    __syncthreads();
    // phase 2: out = hidden @ W2 + b2; store e_out (bf16), atomic recv (fp32)
    {
      float acc[2][4];
#pragma unroll
      for (int c = 0; c < 4; ++c) { acc[0][c] = bb2[c]; acc[1][c] = bb2[c]; }
      for (int k = 0; k < HID; ++k) {
        float4 wp = *(const float4*)&w2[k * 64 + j2];
        float i0 = hid[e2][k], i1 = hid[e2 + 1][k];
        acc[0][0] = fmaf(i0, wp.x, acc[0][0]);  acc[1][0] = fmaf(i1, wp.x, acc[1][0]);
        acc[0][1] = fmaf(i0, wp.y, acc[0][1]);  acc[1][1] = fmaf(i1, wp.y, acc[1][1]);
        acc[0][2] = fmaf(i0, wp.z, acc[0][2]);  acc[1][2] = fmaf(i1, wp.z, acc[1][2]);
        acc[0][3] = fmaf(i0, wp.w, acc[0][3]);  acc[1][3] = fmaf(i1, wp.w, acc[1][3]);
      }
#pragma unroll
      for (int r = 0; r < 2; ++r) {
        const int eg = ebase + e2 + r;
        const int rn = rcv[eg];
        ushort4 st;
        st.x = f2bf(acc[r][0]); st.y = f2bf(acc[r][1]);
        st.z = f2bf(acc[r][2]); st.w = f2bf(acc[r][3]);
        *(ushort4*)&e_out[(long)eg * 64 + j2] = st;
#pragma unroll
        for (int c = 0; c < 4; ++c)
          atomicAdd(&recvbuf[rn * 64 + j2 + c], acc[r][c]);
      }
    }
    __syncthreads();
  }
}

// Node MLP + skip + LayerNorm. in = [h, recv, g] (144). LDS = ins + hid (17.7 KB).
__launch_bounds__(128)
__global__ void node_kernel(float* __restrict__ h, const float* __restrict__ recvbuf,
                            const float* __restrict__ gv,
                            const float* __restrict__ w1, const float* __restrict__ b1,
                            const float* __restrict__ w2, const float* __restrict__ b2,
                            const float* __restrict__ lns, const float* __restrict__ lnb) {
  __shared__ __align__(16) float ins[16][144];
  __shared__ __align__(16) float hid[16][HID + 4];
  const int tid = threadIdx.x;

  const int j1 = (tid & 31) * 4;
  const int e1 = (tid >> 5) * 4;
  const int j2 = (tid & 15) * 4;
  const int e2 = (tid >> 4) * 2;
  float bb1[4], bb2[4], sc[4], bi[4];
#pragma unroll
  for (int c = 0; c < 4; ++c) {
    bb1[c] = b1[j1 + c]; bb2[c] = b2[j2 + c];
    sc[c] = lns[j2 + c]; bi[c] = lnb[j2 + c];
  }

  for (int tile = blockIdx.x; tile < NN / 16; tile += gridDim.x) {
    const int nbase = tile * 16;
    for (int e = 0; e < 16; ++e) {
      const int n = nbase + e;
      for (int c = tid; c < 144; c += 128) {
        float v;
        if (c < 64)       v = h[n * 64 + c];
        else if (c < 128) v = recvbuf[n * 64 + c - 64];
        else              v = gv[c - 128];
        ins[e][c] = v;
      }
    }
    __syncthreads();
    {
      float acc[4][4];
#pragma unroll
      for (int r = 0; r < 4; ++r)
#pragma unroll
        for (int c = 0; c < 4; ++c) acc[r][c] = bb1[c];
      for (int k = 0; k < 144; ++k) {
        float4 wp = *(const float4*)&w1[k * HID + j1];
#pragma unroll
        for (int r = 0; r < 4; ++r) {
          float iv = ins[e1 + r][k];
          acc[r][0] = fmaf(iv, wp.x, acc[r][0]);
          acc[r][1] = fmaf(iv, wp.y, acc[r][1]);
          acc[r][2] = fmaf(iv, wp.z, acc[r][2]);
          acc[r][3] = fmaf(iv, wp.w, acc[r][3]);
        }
      }
#pragma unroll
      for (int r = 0; r < 4; ++r) {
        float4 o;
        o.x = gelu(acc[r][0]); o.y = gelu(acc[r][1]);
        o.z = gelu(acc[r][2]); o.w = gelu(acc[r][3]);
        *(float4*)&hid[e1 + r][j1] = o;
      }
    }
    __syncthreads();
    {
      float acc[2][4];
#pragma unroll
      for (int c = 0; c < 4; ++c) { acc[0][c] = bb2[c]; acc[1][c] = bb2[c]; }
      for (int k = 0; k < HID; ++k) {
        float4 wp = *(const float4*)&w2[k * 64 + j2];
        float i0 = hid[e2][k], i1 = hid[e2 + 1][k];
        acc[0][0] = fmaf(i0, wp.x, acc[0][0]);  acc[1][0] = fmaf(i1, wp.x, acc[1][0]);
        acc[0][1] = fmaf(i0, wp.y, acc[0][1]);  acc[1][1] = fmaf(i1, wp.y, acc[1][1]);
        acc[0][2] = fmaf(i0, wp.z, acc[0][2]);  acc[1][2] = fmaf(i1, wp.z, acc[1][2]);
        acc[0][3] = fmaf(i0, wp.w, acc[0][3]);  acc[1][3] = fmaf(i1, wp.w, acc[1][3]);
      }
#pragma unroll
      for (int r = 0; r < 2; ++r) {
        const int n = nbase + e2 + r;
        float x0 = ins[e2 + r][j2 + 0] + acc[r][0];
        float x1 = ins[e2 + r][j2 + 1] + acc[r][1];
        float x2 = ins[e2 + r][j2 + 2] + acc[r][2];
        float x3 = ins[e2 + r][j2 + 3] + acc[r][3];
        float s = x0 + x1 + x2 + x3;
        float q = x0 * x0 + x1 * x1 + x2 * x2 + x3 * x3;
#pragma unroll
        for (int off = 1; off < 16; off <<= 1) {
          s += __shfl_xor(s, off);
          q += __shfl_xor(q, off);
        }
        float mean = s * (1.0f / 64.0f);
        float var = fmaxf(q * (1.0f / 64.0f) - mean * mean, 0.0f);
        float rstd = rsqrtf(var + 1e-6f);
        float4 o;
        o.x = (x0 - mean) * rstd * sc[0] + bi[0];
        o.y = (x1 - mean) * rstd * sc[1] + bi[1];
        o.z = (x2 - mean) * rstd * sc[2] + bi[2];
        o.w = (x3 - mean) * rstd * sc[3] + bi[3];
        *(float4*)&h[n * 64 + j2] = o;
      }
    }
    __syncthreads();
  }
}

// Output is the reference's dtype: float32 (the test's "bf16" label text is
// hard-coded in its f-string, not a dtype indicator).
__global__ void decode_kernel(const float* __restrict__ h, const float* __restrict__ w,
                              const float* __restrict__ b, float* __restrict__ out) {
  int gid = blockIdx.x * blockDim.x + threadIdx.x;
  if (gid >= NN * INF) return;
  int n = gid / 7, f = gid % 7;
  float acc = b[f];
#pragma unroll
  for (int k = 0; k < LAT; ++k)
    acc = fmaf(h[n * 64 + k], w[k * 7 + f], acc);
  out[gid] = acc;
}

extern "C" void kernel_launch(void* const* d_in, const int* in_sizes, int n_in,
                              void* d_out, int out_size, void* d_ws, size_t ws_size,
                              hipStream_t stream) {
  const float* nodes = (const float*)d_in[0];
  const int* senders = (const int*)d_in[1];
  const int* recvrs  = (const int*)d_in[2];
  const float* g     = (const float*)d_in[3];
  const float* emb_w = (const float*)d_in[4];
  const float* emb_b = (const float*)d_in[5];
  const float* ew1f  = (const float*)d_in[6];
  const float* ew1r  = (const float*)d_in[7];
  const float* eb1   = (const float*)d_in[8];
  const float* ew2   = (const float*)d_in[9];
  const float* eb2   = (const float*)d_in[10];
  const float* nw1   = (const float*)d_in[11];
  const float* nb1   = (const float*)d_in[12];
  const float* nw2   = (const float*)d_in[13];
  const float* nb2   = (const float*)d_in[14];
  const float* lns   = (const float*)d_in[15];
  const float* lnb   = (const float*)d_in[16];
  const float* dw    = (const float*)d_in[17];
  const float* db    = (const float*)d_in[18];

  float* h     = (float*)d_ws;                         // NN*64 fp32 (12.8 MB)
  float* recvb = h + (size_t)NN * LAT;                 // NN*64 fp32 (12.8 MB)
  u16*   ebuf  = (u16*)(recvb + (size_t)NN * LAT);     // NE*64 bf16 (102.4 MB)

  embed_kernel<<<(NN * LAT + 255) / 256, 256, 0, stream>>>(nodes, emb_w, emb_b, h);

  for (int t = 0; t < 3; ++t) {
    zero_kernel<<<(NN * LAT / 4 + 255) / 256, 256, 0, stream>>>((float4*)recvb, NN * LAT / 4);
    if (t == 0)
      edge_kernel<144><<<2048, 128, 0, stream>>>(h, (const u16*)nullptr, ebuf, recvb,
          senders, recvrs, g, ew1f, eb1, ew2, eb2);
    else
      edge_kernel<208><<<2048, 128, 0, stream>>>(h, ebuf, ebuf, recvb,
          senders, recvrs, g, ew1r + (size_t)(t - 1) * 208 * 128,
          eb1 + t * 128, ew2 + t * 128 * 64, eb2 + t * 64);
    node_kernel<<<1024, 128, 0, stream>>>(h, recvb, g,
        nw1 + (size_t)t * 144 * 128, nb1 + t * 128, nw2 + t * 128 * 64, nb2 + t * 64,
        lns + t * 64, lnb + t * 64);
  }

  decode_kernel<<<(NN * INF + 255) / 256, 256, 0, stream>>>(h, dw, db, (float*)d_out);
}

// Round 6
// 1036.427 us; speedup vs baseline: 4.8202x; 4.8202x over previous
//
#include <hip/hip_runtime.h>

#define NN 50000
#define NE 800000
#define INF 7
#define GD 16
#define LAT 64
#define HID 128

typedef unsigned short u16;
typedef __attribute__((ext_vector_type(8))) __bf16 bf16x8;
typedef __attribute__((ext_vector_type(4))) float f32x4;

__device__ __forceinline__ float bf2f(u16 u) {
  union { unsigned int i; float f; } v; v.i = ((unsigned int)u) << 16; return v.f;
}
__device__ __forceinline__ u16 f2bf(float f) {
  union { float f; unsigned int i; } v; v.f = f;
  unsigned int x = v.i;
  return (u16)((x + 0x7fffu + ((x >> 16) & 1u)) >> 16);
}
// jax.nn.gelu default: approximate=True (tanh form)
__device__ __forceinline__ float gelu(float x) {
  float z = 0.7978845608028654f * (x + 0.044715f * x * x * x);
  float e = __expf(2.0f * z);
  float th = 1.0f - 2.0f / (e + 1.0f);
  return 0.5f * x * (1.0f + th);
}

// ---- weight pre-pack: fragment-ordered bf16, K zero-padded to KC*32.
// out[((kc*NT+nt)*64 + lane)*8 + j] = bf16(W[kc*32+(lane>>4)*8+j][nt*16+(lane&15)])
__global__ void pack_w(const float* __restrict__ W, u16* __restrict__ out,
                       int K, int N, int KC) {
  int t = blockIdx.x * blockDim.x + threadIdx.x;
  int NT = N >> 4;
  if (t >= KC * NT * 64) return;
  int l = t & 63;
  int nt = (t >> 6) % NT;
  int kc = t / (64 * NT);
  int n = nt * 16 + (l & 15);
  int kbase = kc * 32 + (l >> 4) * 8;
  ushort4 lo, hi;
  u16 v[8];
#pragma unroll
  for (int j = 0; j < 8; ++j) {
    int k = kbase + j;
    v[j] = (k < K) ? f2bf(W[k * N + n]) : (u16)0;
  }
  lo.x = v[0]; lo.y = v[1]; lo.z = v[2]; lo.w = v[3];
  hi.x = v[4]; hi.y = v[5]; hi.z = v[6]; hi.w = v[7];
  ushort4* dst = (ushort4*)&out[(size_t)t * 8];
  dst[0] = lo; dst[1] = hi;
}

__global__ void cvt_bf(const float* __restrict__ src, u16* __restrict__ dst, int n) {
  int i = blockIdx.x * blockDim.x + threadIdx.x;
  if (i < n) dst[i] = f2bf(src[i]);
}

__global__ void embed_kernel(const float* __restrict__ nodes, const float* __restrict__ w,
                             const float* __restrict__ b, float* __restrict__ h,
                             u16* __restrict__ hbf) {
  int gid = blockIdx.x * blockDim.x + threadIdx.x;
  if (gid >= NN * LAT) return;
  int n = gid >> 6, j = gid & 63;
  float acc = b[j];
#pragma unroll
  for (int k = 0; k < INF; ++k)
    acc = fmaf(nodes[n * INF + k], w[k * LAT + j], acc);
  h[gid] = acc;
  hbf[gid] = f2bf(acc);
}

__global__ void zero_kernel(float4* __restrict__ p, int n4) {
  int i = blockIdx.x * blockDim.x + threadIdx.x;
  if (i < n4) p[i] = make_float4(0.f, 0.f, 0.f, 0.f);
}

// ---- MFMA edge MLP. 32 edges/block, 256 threads = 4 waves.
// ins row (u16): FIRST: [s 64][r 64][g 16][pad] K=160=5*32
//           else: [e 64][s 64][r 64][g 16][pad] K=224=7*32
template <int KC, bool FIRST>
__launch_bounds__(256)
__global__ void edge_mfma(const u16* __restrict__ hbf, u16* __restrict__ ebuf,
                          float* __restrict__ recvbuf,
                          const int* __restrict__ snd, const int* __restrict__ rcv,
                          const u16* __restrict__ gbf,
                          const u16* __restrict__ w1p, const float* __restrict__ b1,
                          const u16* __restrict__ w2p, const float* __restrict__ b2) {
  constexpr int STRIDE = KC * 32 + 8;   // u16; *2B is a multiple of 16
  constexpr int CH = KC * 4 + 1;        // 16B chunks per ins row
  __shared__ __align__(16) u16 ins[32 * STRIDE];
  __shared__ __align__(16) u16 hid[32 * 136];
  __shared__ __align__(16) u16 easm[32 * 64];
  __shared__ int rcvs[32];

  const int tid = threadIdx.x;
  const int lane = tid & 63;
  const int w = tid >> 6;
  const int l15 = lane & 15;
  const int q = lane >> 4;

  // phase 1: wave w -> row-tile mr1=w&1, col-tiles ntb1..ntb1+3 (of 8)
  const int mr1 = w & 1;
  const int ntb1 = (w >> 1) * 4;
  float bb1[4];
#pragma unroll
  for (int i = 0; i < 4; ++i) bb1[i] = b1[(ntb1 + i) * 16 + l15];
  // phase 2: wave w -> mr2=w&1, col-tiles ntb2..ntb2+1 (of 4)
  const int mr2 = w & 1;
  const int ntb2 = (w >> 1) * 2;
  float bb2[2];
#pragma unroll
  for (int i = 0; i < 2; ++i) bb2[i] = b2[(ntb2 + i) * 16 + l15];

  for (int tile = blockIdx.x; tile < NE / 32; tile += gridDim.x) {
    const int ebase = tile * 32;
    __syncthreads();   // protect ins/easm reuse from previous iteration
    // --- stage inputs: 8 threads per edge, 16B chunks
    {
      const int e = tid >> 3;
      const int sub = tid & 7;
      const int eg = ebase + e;
      const int s = snd[eg], r = rcv[eg];
      if (tid < 32) rcvs[tid] = rcv[ebase + tid];
      uint4* dst = (uint4*)&ins[e * STRIDE];
      const uint4* srcs = (const uint4*)&hbf[(size_t)s * 64];
      const uint4* srcr = (const uint4*)&hbf[(size_t)r * 64];
      const uint4* srcg = (const uint4*)gbf;
      if (FIRST) {
        for (int c = sub; c < CH; c += 8) {
          uint4 v;
          if (c < 8)        v = srcs[c];
          else if (c < 16)  v = srcr[c - 8];
          else if (c < 18)  v = srcg[c - 16];
          else              v = make_uint4(0, 0, 0, 0);
          dst[c] = v;
        }
      } else {
        const uint4* srce = (const uint4*)&ebuf[(size_t)eg * 64];
        for (int c = sub; c < CH; c += 8) {
          uint4 v;
          if (c < 8)        v = srce[c];
          else if (c < 16)  v = srcs[c - 8];
          else if (c < 24)  v = srcr[c - 16];
          else if (c < 26)  v = srcg[c - 24];
          else              v = make_uint4(0, 0, 0, 0);
          dst[c] = v;
        }
      }
    }
    __syncthreads();
    // --- phase 1: hid = gelu(ins @ W1 + b1)   [32 x 128]
    {
      f32x4 acc[4];
#pragma unroll
      for (int i = 0; i < 4; ++i) acc[i] = (f32x4){bb1[i], bb1[i], bb1[i], bb1[i]};
      const int arow = mr1 * 16 + l15;
      for (int kc = 0; kc < KC; ++kc) {
        bf16x8 a = *(const bf16x8*)&ins[arow * STRIDE + kc * 32 + q * 8];
#pragma unroll
        for (int i = 0; i < 4; ++i) {
          bf16x8 b = *(const bf16x8*)&w1p[(size_t)((kc * 8 + ntb1 + i) * 64 + lane) * 8];
          acc[i] = __builtin_amdgcn_mfma_f32_16x16x32_bf16(a, b, acc[i], 0, 0, 0);
        }
      }
#pragma unroll
      for (int i = 0; i < 4; ++i) {
        const int col = (ntb1 + i) * 16 + l15;
#pragma unroll
        for (int r4 = 0; r4 < 4; ++r4) {
          const int row = mr1 * 16 + q * 4 + r4;
          hid[row * 136 + col] = f2bf(gelu(acc[i][r4]));
        }
      }
    }
    __syncthreads();
    // --- phase 2: out = hid @ W2 + b2   [32 x 64]; atomics + easm
    {
      f32x4 acc[2];
#pragma unroll
      for (int i = 0; i < 2; ++i) acc[i] = (f32x4){bb2[i], bb2[i], bb2[i], bb2[i]};
      const int arow = mr2 * 16 + l15;
      for (int kc = 0; kc < 4; ++kc) {
        bf16x8 a = *(const bf16x8*)&hid[arow * 136 + kc * 32 + q * 8];
#pragma unroll
        for (int i = 0; i < 2; ++i) {
          bf16x8 b = *(const bf16x8*)&w2p[(size_t)((kc * 4 + ntb2 + i) * 64 + lane) * 8];
          acc[i] = __builtin_amdgcn_mfma_f32_16x16x32_bf16(a, b, acc[i], 0, 0, 0);
        }
      }
#pragma unroll
      for (int i = 0; i < 2; ++i) {
        const int col = (ntb2 + i) * 16 + l15;
#pragma unroll
        for (int r4 = 0; r4 < 4; ++r4) {
          const int row = mr2 * 16 + q * 4 + r4;
          const float v = acc[i][r4];
          easm[row * 64 + col] = f2bf(v);
          atomicAdd(&recvbuf[(size_t)rcvs[row] * 64 + col], v);
        }
      }
    }
    __syncthreads();
    // --- coalesced e_out write: 256 threads x 16B = 32 rows x 128B
    ((uint4*)&ebuf[(size_t)ebase * 64])[tid] = ((const uint4*)easm)[tid];
  }
}

// Node MLP + skip + LayerNorm (fp32 VALU; ~5% of time). Also refreshes hbf.
__launch_bounds__(128)
__global__ void node_kernel(float* __restrict__ h, u16* __restrict__ hbf,
                            const float* __restrict__ recvbuf,
                            const float* __restrict__ gv,
                            const float* __restrict__ w1, const float* __restrict__ b1,
                            const float* __restrict__ w2, const float* __restrict__ b2,
                            const float* __restrict__ lns, const float* __restrict__ lnb) {
  __shared__ __align__(16) float ins[16][144];
  __shared__ __align__(16) float hid[16][HID + 4];
  const int tid = threadIdx.x;

  const int j1 = (tid & 31) * 4;
  const int e1 = (tid >> 5) * 4;
  const int j2 = (tid & 15) * 4;
  const int e2 = (tid >> 4) * 2;
  float bb1[4], bb2[4], sc[4], bi[4];
#pragma unroll
  for (int c = 0; c < 4; ++c) {
    bb1[c] = b1[j1 + c]; bb2[c] = b2[j2 + c];
    sc[c] = lns[j2 + c]; bi[c] = lnb[j2 + c];
  }

  for (int tile = blockIdx.x; tile < NN / 16; tile += gridDim.x) {
    const int nbase = tile * 16;
    for (int e = 0; e < 16; ++e) {
      const int n = nbase + e;
      for (int c = tid; c < 144; c += 128) {
        float v;
        if (c < 64)       v = h[n * 64 + c];
        else if (c < 128) v = recvbuf[n * 64 + c - 64];
        else              v = gv[c - 128];
        ins[e][c] = v;
      }
    }
    __syncthreads();
    {
      float acc[4][4];
#pragma unroll
      for (int r = 0; r < 4; ++r)
#pragma unroll
        for (int c = 0; c < 4; ++c) acc[r][c] = bb1[c];
      for (int k = 0; k < 144; ++k) {
        float4 wp = *(const float4*)&w1[k * HID + j1];
#pragma unroll
        for (int r = 0; r < 4; ++r) {
          float iv = ins[e1 + r][k];
          acc[r][0] = fmaf(iv, wp.x, acc[r][0]);
          acc[r][1] = fmaf(iv, wp.y, acc[r][1]);
          acc[r][2] = fmaf(iv, wp.z, acc[r][2]);
          acc[r][3] = fmaf(iv, wp.w, acc[r][3]);
        }
      }
#pragma unroll
      for (int r = 0; r < 4; ++r) {
        float4 o;
        o.x = gelu(acc[r][0]); o.y = gelu(acc[r][1]);
        o.z = gelu(acc[r][2]); o.w = gelu(acc[r][3]);
        *(float4*)&hid[e1 + r][j1] = o;
      }
    }
    __syncthreads();
    {
      float acc[2][4];
#pragma unroll
      for (int c = 0; c < 4; ++c) { acc[0][c] = bb2[c]; acc[1][c] = bb2[c]; }
      for (int k = 0; k < HID; ++k) {
        float4 wp = *(const float4*)&w2[k * 64 + j2];
        float i0 = hid[e2][k], i1 = hid[e2 + 1][k];
        acc[0][0] = fmaf(i0, wp.x, acc[0][0]);  acc[1][0] = fmaf(i1, wp.x, acc[1][0]);
        acc[0][1] = fmaf(i0, wp.y, acc[0][1]);  acc[1][1] = fmaf(i1, wp.y, acc[1][1]);
        acc[0][2] = fmaf(i0, wp.z, acc[0][2]);  acc[1][2] = fmaf(i1, wp.z, acc[1][2]);
        acc[0][3] = fmaf(i0, wp.w, acc[0][3]);  acc[1][3] = fmaf(i1, wp.w, acc[1][3]);
      }
#pragma unroll
      for (int r = 0; r < 2; ++r) {
        const int n = nbase + e2 + r;
        float x0 = ins[e2 + r][j2 + 0] + acc[r][0];
        float x1 = ins[e2 + r][j2 + 1] + acc[r][1];
        float x2 = ins[e2 + r][j2 + 2] + acc[r][2];
        float x3 = ins[e2 + r][j2 + 3] + acc[r][3];
        float s = x0 + x1 + x2 + x3;
        float qq = x0 * x0 + x1 * x1 + x2 * x2 + x3 * x3;
#pragma unroll
        for (int off = 1; off < 16; off <<= 1) {
          s += __shfl_xor(s, off);
          qq += __shfl_xor(qq, off);
        }
        float mean = s * (1.0f / 64.0f);
        float var = fmaxf(qq * (1.0f / 64.0f) - mean * mean, 0.0f);
        float rstd = rsqrtf(var + 1e-6f);
        float4 o;
        o.x = (x0 - mean) * rstd * sc[0] + bi[0];
        o.y = (x1 - mean) * rstd * sc[1] + bi[1];
        o.z = (x2 - mean) * rstd * sc[2] + bi[2];
        o.w = (x3 - mean) * rstd * sc[3] + bi[3];
        *(float4*)&h[n * 64 + j2] = o;
        ushort4 ob;
        ob.x = f2bf(o.x); ob.y = f2bf(o.y); ob.z = f2bf(o.z); ob.w = f2bf(o.w);
        *(ushort4*)&hbf[n * 64 + j2] = ob;
      }
    }
    __syncthreads();
  }
}

// Output dtype: float32 (reference returns fp32).
__global__ void decode_kernel(const float* __restrict__ h, const float* __restrict__ w,
                              const float* __restrict__ b, float* __restrict__ out) {
  int gid = blockIdx.x * blockDim.x + threadIdx.x;
  if (gid >= NN * INF) return;
  int n = gid / 7, f = gid % 7;
  float acc = b[f];
#pragma unroll
  for (int k = 0; k < LAT; ++k)
    acc = fmaf(h[n * 64 + k], w[k * 7 + f], acc);
  out[gid] = acc;
}

extern "C" void kernel_launch(void* const* d_in, const int* in_sizes, int n_in,
                              void* d_out, int out_size, void* d_ws, size_t ws_size,
                              hipStream_t stream) {
  const float* nodes = (const float*)d_in[0];
  const int* senders = (const int*)d_in[1];
  const int* recvrs  = (const int*)d_in[2];
  const float* g     = (const float*)d_in[3];
  const float* emb_w = (const float*)d_in[4];
  const float* emb_b = (const float*)d_in[5];
  const float* ew1f  = (const float*)d_in[6];
  const float* ew1r  = (const float*)d_in[7];
  const float* eb1   = (const float*)d_in[8];
  const float* ew2   = (const float*)d_in[9];
  const float* eb2   = (const float*)d_in[10];
  const float* nw1   = (const float*)d_in[11];
  const float* nb1   = (const float*)d_in[12];
  const float* nw2   = (const float*)d_in[13];
  const float* nb2   = (const float*)d_in[14];
  const float* lns   = (const float*)d_in[15];
  const float* lnb   = (const float*)d_in[16];
  const float* dw    = (const float*)d_in[17];
  const float* db    = (const float*)d_in[18];

  char* cur = (char*)d_ws;
  float* h     = (float*)cur;  cur += (size_t)NN * LAT * 4;        // 12.8 MB
  float* recvb = (float*)cur;  cur += (size_t)NN * LAT * 4;        // 12.8 MB
  u16*   ebuf  = (u16*)cur;    cur += (size_t)NE * LAT * 2;        // 102.4 MB
  u16*   hbf   = (u16*)cur;    cur += (size_t)NN * LAT * 2;        // 6.4 MB
  u16*   w1p[3]; for (int t = 0; t < 3; ++t) { w1p[t] = (u16*)cur; cur += 7 * 8 * 64 * 8 * 2; }
  u16*   w2p[3]; for (int t = 0; t < 3; ++t) { w2p[t] = (u16*)cur; cur += 4 * 4 * 64 * 8 * 2; }
  u16*   gbf   = (u16*)cur;    cur += 32;

  // pre-pack weights (per launch; graph-capture safe)
  pack_w<<<(5 * 8 * 64 + 255) / 256, 256, 0, stream>>>(ew1f, w1p[0], 144, 128, 5);
  pack_w<<<(7 * 8 * 64 + 255) / 256, 256, 0, stream>>>(ew1r, w1p[1], 208, 128, 7);
  pack_w<<<(7 * 8 * 64 + 255) / 256, 256, 0, stream>>>(ew1r + (size_t)208 * 128, w1p[2], 208, 128, 7);
  for (int t = 0; t < 3; ++t)
    pack_w<<<(4 * 4 * 64 + 255) / 256, 256, 0, stream>>>(ew2 + (size_t)t * 128 * 64, w2p[t], 128, 64, 4);
  cvt_bf<<<1, 64, 0, stream>>>(g, gbf, GD);

  embed_kernel<<<(NN * LAT + 255) / 256, 256, 0, stream>>>(nodes, emb_w, emb_b, h, hbf);

  for (int t = 0; t < 3; ++t) {
    zero_kernel<<<(NN * LAT / 4 + 255) / 256, 256, 0, stream>>>((float4*)recvb, NN * LAT / 4);
    if (t == 0)
      edge_mfma<5, true><<<2048, 256, 0, stream>>>(hbf, ebuf, recvb,
          senders, recvrs, gbf, w1p[0], eb1, w2p[0], eb2);
    else
      edge_mfma<7, false><<<2048, 256, 0, stream>>>(hbf, ebuf, recvb,
          senders, recvrs, gbf, w1p[t], eb1 + t * 128, w2p[t], eb2 + t * 64);
    node_kernel<<<1024, 128, 0, stream>>>(h, hbf, recvb, g,
        nw1 + (size_t)t * 144 * 128, nb1 + t * 128, nw2 + t * 128 * 64, nb2 + t * 64,
        lns + t * 64, lnb + t * 64);
  }

  decode_kernel<<<(NN * INF + 255) / 256, 256, 0, stream>>>(h, dw, db, (float*)d_out);
}

// Round 7
// 842.386 us; speedup vs baseline: 5.9305x; 1.2303x over previous
//
#include <hip/hip_runtime.h>

#define NN 50000
#define NE 800000
#define INF 7
#define GD 16
#define LAT 64
#define HID 128

typedef unsigned short u16;
typedef __attribute__((ext_vector_type(8))) __bf16 bf16x8;
typedef __attribute__((ext_vector_type(4))) float f32x4;

__device__ __forceinline__ float bf2f(u16 u) {
  union { unsigned int i; float f; } v; v.i = ((unsigned int)u) << 16; return v.f;
}
__device__ __forceinline__ u16 f2bf(float f) {
  union { float f; unsigned int i; } v; v.f = f;
  unsigned int x = v.i;
  return (u16)((x + 0x7fffu + ((x >> 16) & 1u)) >> 16);
}
// jax.nn.gelu default: approximate=True (tanh form)
__device__ __forceinline__ float gelu(float x) {
  float z = 0.7978845608028654f * (x + 0.044715f * x * x * x);
  float e = __expf(2.0f * z);
  float th = 1.0f - 2.0f / (e + 1.0f);
  return 0.5f * x * (1.0f + th);
}

// ---- weight pre-pack: fragment-ordered bf16, K zero-padded to KC*32.
// out[((kc*NT+nt)*64 + lane)*8 + j] = bf16(W[kc*32+(lane>>4)*8+j][nt*16+(lane&15)])
__global__ void pack_w(const float* __restrict__ W, u16* __restrict__ out,
                       int K, int N, int KC) {
  int t = blockIdx.x * blockDim.x + threadIdx.x;
  int NT = N >> 4;
  if (t >= KC * NT * 64) return;
  int l = t & 63;
  int nt = (t >> 6) % NT;
  int kc = t / (64 * NT);
  int n = nt * 16 + (l & 15);
  int kbase = kc * 32 + (l >> 4) * 8;
  ushort4 lo, hi;
  u16 v[8];
#pragma unroll
  for (int j = 0; j < 8; ++j) {
    int k = kbase + j;
    v[j] = (k < K) ? f2bf(W[k * N + n]) : (u16)0;
  }
  lo.x = v[0]; lo.y = v[1]; lo.z = v[2]; lo.w = v[3];
  hi.x = v[4]; hi.y = v[5]; hi.z = v[6]; hi.w = v[7];
  ushort4* dst = (ushort4*)&out[(size_t)t * 8];
  dst[0] = lo; dst[1] = hi;
}

// g -> bf16, zero-padded to 32 entries (A-frags with q>=2 read zeros)
__global__ void g_pack(const float* __restrict__ g, u16* __restrict__ dst) {
  int i = threadIdx.x;
  if (i < 32) dst[i] = (i < GD) ? f2bf(g[i]) : (u16)0;
}

// fp32 -> bf16 bulk convert (recvbuf shadow)
__global__ void cvt_bf4(const float4* __restrict__ src, ushort4* __restrict__ dst, int n4) {
  int i = blockIdx.x * blockDim.x + threadIdx.x;
  if (i >= n4) return;
  float4 v = src[i];
  ushort4 o;
  o.x = f2bf(v.x); o.y = f2bf(v.y); o.z = f2bf(v.z); o.w = f2bf(v.w);
  dst[i] = o;
}

__global__ void embed_kernel(const float* __restrict__ nodes, const float* __restrict__ w,
                             const float* __restrict__ b, float* __restrict__ h,
                             u16* __restrict__ hbf) {
  int gid = blockIdx.x * blockDim.x + threadIdx.x;
  if (gid >= NN * LAT) return;
  int n = gid >> 6, j = gid & 63;
  float acc = b[j];
#pragma unroll
  for (int k = 0; k < INF; ++k)
    acc = fmaf(nodes[n * INF + k], w[k * LAT + j], acc);
  h[gid] = acc;
  hbf[gid] = f2bf(acc);
}

__global__ void zero_kernel(float4* __restrict__ p, int n4) {
  int i = blockIdx.x * blockDim.x + threadIdx.x;
  if (i < n4) p[i] = make_float4(0.f, 0.f, 0.f, 0.f);
}

// ---- MFMA edge MLP v2: NO ins staging. A-fragments (16B/lane) loaded
// directly from global: segment choice is wave-uniform per unrolled kc.
// K layout FIRST: [s 64][r 64][g 16|pad] = 160 (KC=5)
//          else : [e 64][s 64][r 64][g 16|pad] = 224 (KC=7)
template <int KC, bool FIRST>
__launch_bounds__(256)
__global__ void edge_mfma(const u16* __restrict__ hbf, u16* __restrict__ ebuf,
                          float* __restrict__ recvbuf,
                          const int* __restrict__ snd, const int* __restrict__ rcv,
                          const u16* __restrict__ gpad,
                          const u16* __restrict__ w1p, const float* __restrict__ b1,
                          const u16* __restrict__ w2p, const float* __restrict__ b2) {
  __shared__ __align__(16) u16 hid[32 * 136];
  __shared__ __align__(16) u16 easm[32 * 64];
  __shared__ int rcvs[32];

  const int tid = threadIdx.x;
  const int lane = tid & 63;
  const int w = tid >> 6;
  const int l15 = lane & 15;
  const int q = lane >> 4;
  const int mr = w & 1;              // row-tile (16 rows) for both phases
  const int ntb1 = (w >> 1) * 4;     // phase-1 col-tiles (4 of 8)
  const int ntb2 = (w >> 1) * 2;     // phase-2 col-tiles (2 of 4)
  const int arow = mr * 16 + l15;

  float bb1[4], bb2[2];
#pragma unroll
  for (int i = 0; i < 4; ++i) bb1[i] = b1[(ntb1 + i) * 16 + l15];
#pragma unroll
  for (int i = 0; i < 2; ++i) bb2[i] = b2[(ntb2 + i) * 16 + l15];

  for (int tile = blockIdx.x; tile < NE / 32; tile += gridDim.x) {
    const int ebase = tile * 32;
    const int eg = ebase + arow;
    const int soff = snd[eg] * 64;
    const int roff = rcv[eg] * 64;
    if (tid < 32) rcvs[tid] = rcv[ebase + tid];

    // --- phase 1: hid = gelu(in @ W1 + b1)   [32 x 128]
    {
      f32x4 acc[4];
#pragma unroll
      for (int i = 0; i < 4; ++i) acc[i] = (f32x4){bb1[i], bb1[i], bb1[i], bb1[i]};
#pragma unroll
      for (int kc = 0; kc < KC; ++kc) {
        const u16* abase;
        if (FIRST) {
          abase = (kc < 2) ? &hbf[soff + kc * 32]
                : (kc < 4) ? &hbf[roff + (kc - 2) * 32]
                :            &gpad[0];
        } else {
          abase = (kc < 2) ? &ebuf[(size_t)eg * 64 + kc * 32]
                : (kc < 4) ? &hbf[soff + (kc - 2) * 32]
                : (kc < 6) ? &hbf[roff + (kc - 4) * 32]
                :            &gpad[0];
        }
        bf16x8 a = *(const bf16x8*)&abase[q * 8];
#pragma unroll
        for (int i = 0; i < 4; ++i) {
          bf16x8 b = *(const bf16x8*)&w1p[(size_t)((kc * 8 + ntb1 + i) * 64 + lane) * 8];
          acc[i] = __builtin_amdgcn_mfma_f32_16x16x32_bf16(a, b, acc[i], 0, 0, 0);
        }
      }
#pragma unroll
      for (int i = 0; i < 4; ++i) {
        const int col = (ntb1 + i) * 16 + l15;
#pragma unroll
        for (int r4 = 0; r4 < 4; ++r4) {
          const int row = mr * 16 + q * 4 + r4;
          hid[row * 136 + col] = f2bf(gelu(acc[i][r4]));
        }
      }
    }
    __syncthreads();
    // --- phase 2: out = hid @ W2 + b2   [32 x 64]; easm + atomics
    {
      f32x4 acc[2];
#pragma unroll
      for (int i = 0; i < 2; ++i) acc[i] = (f32x4){bb2[i], bb2[i], bb2[i], bb2[i]};
#pragma unroll
      for (int kc = 0; kc < 4; ++kc) {
        bf16x8 a = *(const bf16x8*)&hid[arow * 136 + kc * 32 + q * 8];
#pragma unroll
        for (int i = 0; i < 2; ++i) {
          bf16x8 b = *(const bf16x8*)&w2p[(size_t)((kc * 4 + ntb2 + i) * 64 + lane) * 8];
          acc[i] = __builtin_amdgcn_mfma_f32_16x16x32_bf16(a, b, acc[i], 0, 0, 0);
        }
      }
#pragma unroll
      for (int i = 0; i < 2; ++i) {
        const int col = (ntb2 + i) * 16 + l15;
#pragma unroll
        for (int r4 = 0; r4 < 4; ++r4) {
          const int row = mr * 16 + q * 4 + r4;
          const float v = acc[i][r4];
          easm[row * 64 + col] = f2bf(v);
          atomicAdd(&recvbuf[(size_t)rcvs[row] * 64 + col], v);
        }
      }
    }
    __syncthreads();
    // --- coalesced e_out write: 256 threads x 16B = 32 rows x 128B
    ((uint4*)&ebuf[(size_t)ebase * 64])[tid] = ((const uint4*)easm)[tid];
  }
}

// ---- MFMA node MLP + skip + LayerNorm. 32 nodes/block.
// K layout: [h 64][recv 64][g 16|pad] = 160 (KC=5); phase2 K=128.
__launch_bounds__(256)
__global__ void node_mfma(float* __restrict__ h, u16* __restrict__ hbf,
                          const u16* __restrict__ recvbf,
                          const u16* __restrict__ gpad,
                          const u16* __restrict__ w1p, const float* __restrict__ b1,
                          const u16* __restrict__ w2p, const float* __restrict__ b2,
                          const float* __restrict__ lns, const float* __restrict__ lnb) {
  __shared__ __align__(16) u16 hid[32 * 136];
  __shared__ __align__(16) float outs[32 * 68];

  const int tid = threadIdx.x;
  const int lane = tid & 63;
  const int w = tid >> 6;
  const int l15 = lane & 15;
  const int q = lane >> 4;
  const int mr = w & 1;
  const int ntb1 = (w >> 1) * 4;
  const int ntb2 = (w >> 1) * 2;
  const int arow = mr * 16 + l15;

  float bb1[4], bb2[2];
#pragma unroll
  for (int i = 0; i < 4; ++i) bb1[i] = b1[(ntb1 + i) * 16 + l15];
#pragma unroll
  for (int i = 0; i < 2; ++i) bb2[i] = b2[(ntb2 + i) * 16 + l15];

  // LN per-thread constants: row nrow = tid>>3, cols jc..jc+7
  const int nrow = tid >> 3;
  const int jc = (tid & 7) * 8;
  float sc8[8], bi8[8];
#pragma unroll
  for (int k = 0; k < 8; ++k) { sc8[k] = lns[jc + k]; bi8[k] = lnb[jc + k]; }

  const int NT = (NN + 31) / 32;
  for (int tile = blockIdx.x; tile < NT; tile += gridDim.x) {
    const int nbase = tile * 32;
    const int na = min(nbase + arow, NN - 1) * 64;   // clamped A-row offset

    // --- phase 1
    {
      f32x4 acc[4];
#pragma unroll
      for (int i = 0; i < 4; ++i) acc[i] = (f32x4){bb1[i], bb1[i], bb1[i], bb1[i]};
#pragma unroll
      for (int kc = 0; kc < 5; ++kc) {
        const u16* abase = (kc < 2) ? &hbf[na + kc * 32]
                         : (kc < 4) ? &recvbf[na + (kc - 2) * 32]
                         :            &gpad[0];
        bf16x8 a = *(const bf16x8*)&abase[q * 8];
#pragma unroll
        for (int i = 0; i < 4; ++i) {
          bf16x8 b = *(const bf16x8*)&w1p[(size_t)((kc * 8 + ntb1 + i) * 64 + lane) * 8];
          acc[i] = __builtin_amdgcn_mfma_f32_16x16x32_bf16(a, b, acc[i], 0, 0, 0);
        }
      }
#pragma unroll
      for (int i = 0; i < 4; ++i) {
        const int col = (ntb1 + i) * 16 + l15;
#pragma unroll
        for (int r4 = 0; r4 < 4; ++r4) {
          const int row = mr * 16 + q * 4 + r4;
          hid[row * 136 + col] = f2bf(gelu(acc[i][r4]));
        }
      }
    }
    __syncthreads();
    // --- phase 2: upd = hid @ W2 + b2 -> outs (fp32 LDS)
    {
      f32x4 acc[2];
#pragma unroll
      for (int i = 0; i < 2; ++i) acc[i] = (f32x4){bb2[i], bb2[i], bb2[i], bb2[i]};
#pragma unroll
      for (int kc = 0; kc < 4; ++kc) {
        bf16x8 a = *(const bf16x8*)&hid[arow * 136 + kc * 32 + q * 8];
#pragma unroll
        for (int i = 0; i < 2; ++i) {
          bf16x8 b = *(const bf16x8*)&w2p[(size_t)((kc * 4 + ntb2 + i) * 64 + lane) * 8];
          acc[i] = __builtin_amdgcn_mfma_f32_16x16x32_bf16(a, b, acc[i], 0, 0, 0);
        }
      }
#pragma unroll
      for (int i = 0; i < 2; ++i) {
        const int col = (ntb2 + i) * 16 + l15;
#pragma unroll
        for (int r4 = 0; r4 < 4; ++r4) {
          const int row = mr * 16 + q * 4 + r4;
          outs[row * 68 + col] = acc[i][r4];
        }
      }
    }
    __syncthreads();
    // --- skip + LayerNorm: 8 threads per node row, 8 cols each
    {
      const int n = nbase + nrow;
      if (n < NN) {
        float x[8];
        float4 hv0 = *(const float4*)&h[n * 64 + jc];
        float4 hv1 = *(const float4*)&h[n * 64 + jc + 4];
        x[0] = hv0.x + outs[nrow * 68 + jc + 0];
        x[1] = hv0.y + outs[nrow * 68 + jc + 1];
        x[2] = hv0.z + outs[nrow * 68 + jc + 2];
        x[3] = hv0.w + outs[nrow * 68 + jc + 3];
        x[4] = hv1.x + outs[nrow * 68 + jc + 4];
        x[5] = hv1.y + outs[nrow * 68 + jc + 5];
        x[6] = hv1.z + outs[nrow * 68 + jc + 6];
        x[7] = hv1.w + outs[nrow * 68 + jc + 7];
        float s = 0.f, qq = 0.f;
#pragma unroll
        for (int k = 0; k < 8; ++k) { s += x[k]; qq += x[k] * x[k]; }
#pragma unroll
        for (int off = 1; off < 8; off <<= 1) {
          s += __shfl_xor(s, off);
          qq += __shfl_xor(qq, off);
        }
        float mean = s * (1.0f / 64.0f);
        float var = fmaxf(qq * (1.0f / 64.0f) - mean * mean, 0.0f);
        float rstd = rsqrtf(var + 1e-6f);
        float o[8];
        ushort4 ob0, ob1;
#pragma unroll
        for (int k = 0; k < 8; ++k) o[k] = (x[k] - mean) * rstd * sc8[k] + bi8[k];
        *(float4*)&h[n * 64 + jc]     = make_float4(o[0], o[1], o[2], o[3]);
        *(float4*)&h[n * 64 + jc + 4] = make_float4(o[4], o[5], o[6], o[7]);
        ob0.x = f2bf(o[0]); ob0.y = f2bf(o[1]); ob0.z = f2bf(o[2]); ob0.w = f2bf(o[3]);
        ob1.x = f2bf(o[4]); ob1.y = f2bf(o[5]); ob1.z = f2bf(o[6]); ob1.w = f2bf(o[7]);
        *(ushort4*)&hbf[n * 64 + jc]     = ob0;
        *(ushort4*)&hbf[n * 64 + jc + 4] = ob1;
      }
    }
    __syncthreads();   // protect hid/outs reuse next tile
  }
}

// Output dtype: float32 (reference returns fp32).
__global__ void decode_kernel(const float* __restrict__ h, const float* __restrict__ w,
                              const float* __restrict__ b, float* __restrict__ out) {
  int gid = blockIdx.x * blockDim.x + threadIdx.x;
  if (gid >= NN * INF) return;
  int n = gid / 7, f = gid % 7;
  float acc = b[f];
#pragma unroll
  for (int k = 0; k < LAT; ++k)
    acc = fmaf(h[n * 64 + k], w[k * 7 + f], acc);
  out[gid] = acc;
}

extern "C" void kernel_launch(void* const* d_in, const int* in_sizes, int n_in,
                              void* d_out, int out_size, void* d_ws, size_t ws_size,
                              hipStream_t stream) {
  const float* nodes = (const float*)d_in[0];
  const int* senders = (const int*)d_in[1];
  const int* recvrs  = (const int*)d_in[2];
  const float* g     = (const float*)d_in[3];
  const float* emb_w = (const float*)d_in[4];
  const float* emb_b = (const float*)d_in[5];
  const float* ew1f  = (const float*)d_in[6];
  const float* ew1r  = (const float*)d_in[7];
  const float* eb1   = (const float*)d_in[8];
  const float* ew2   = (const float*)d_in[9];
  const float* eb2   = (const float*)d_in[10];
  const float* nw1   = (const float*)d_in[11];
  const float* nb1   = (const float*)d_in[12];
  const float* nw2   = (const float*)d_in[13];
  const float* nb2   = (const float*)d_in[14];
  const float* lns   = (const float*)d_in[15];
  const float* lnb   = (const float*)d_in[16];
  const float* dw    = (const float*)d_in[17];
  const float* db    = (const float*)d_in[18];

  char* cur = (char*)d_ws;
  float* h      = (float*)cur;  cur += (size_t)NN * LAT * 4;        // 12.8 MB
  float* recvb  = (float*)cur;  cur += (size_t)NN * LAT * 4;        // 12.8 MB
  u16*   ebuf   = (u16*)cur;    cur += (size_t)NE * LAT * 2;        // 102.4 MB
  u16*   hbf    = (u16*)cur;    cur += (size_t)NN * LAT * 2;        // 6.4 MB
  u16*   recvbf = (u16*)cur;    cur += (size_t)NN * LAT * 2;        // 6.4 MB
  u16*   ew1p[3]; for (int t = 0; t < 3; ++t) { ew1p[t] = (u16*)cur; cur += 7 * 8 * 64 * 8 * 2; }
  u16*   ew2p[3]; for (int t = 0; t < 3; ++t) { ew2p[t] = (u16*)cur; cur += 4 * 4 * 64 * 8 * 2; }
  u16*   nw1p[3]; for (int t = 0; t < 3; ++t) { nw1p[t] = (u16*)cur; cur += 5 * 8 * 64 * 8 * 2; }
  u16*   nw2p[3]; for (int t = 0; t < 3; ++t) { nw2p[t] = (u16*)cur; cur += 4 * 4 * 64 * 8 * 2; }
  u16*   gpad   = (u16*)cur;    cur += 64;

  // pre-pack weights (per launch; graph-capture safe)
  pack_w<<<(5 * 8 * 64 + 255) / 256, 256, 0, stream>>>(ew1f, ew1p[0], 144, 128, 5);
  pack_w<<<(7 * 8 * 64 + 255) / 256, 256, 0, stream>>>(ew1r, ew1p[1], 208, 128, 7);
  pack_w<<<(7 * 8 * 64 + 255) / 256, 256, 0, stream>>>(ew1r + (size_t)208 * 128, ew1p[2], 208, 128, 7);
  for (int t = 0; t < 3; ++t) {
    pack_w<<<(4 * 4 * 64 + 255) / 256, 256, 0, stream>>>(ew2 + (size_t)t * 128 * 64, ew2p[t], 128, 64, 4);
    pack_w<<<(5 * 8 * 64 + 255) / 256, 256, 0, stream>>>(nw1 + (size_t)t * 144 * 128, nw1p[t], 144, 128, 5);
    pack_w<<<(4 * 4 * 64 + 255) / 256, 256, 0, stream>>>(nw2 + (size_t)t * 128 * 64, nw2p[t], 128, 64, 4);
  }
  g_pack<<<1, 64, 0, stream>>>(g, gpad);

  embed_kernel<<<(NN * LAT + 255) / 256, 256, 0, stream>>>(nodes, emb_w, emb_b, h, hbf);

  for (int t = 0; t < 3; ++t) {
    zero_kernel<<<(NN * LAT / 4 + 255) / 256, 256, 0, stream>>>((float4*)recvb, NN * LAT / 4);
    if (t == 0)
      edge_mfma<5, true><<<2048, 256, 0, stream>>>(hbf, ebuf, recvb,
          senders, recvrs, gpad, ew1p[0], eb1, ew2p[0], eb2);
    else
      edge_mfma<7, false><<<2048, 256, 0, stream>>>(hbf, ebuf, recvb,
          senders, recvrs, gpad, ew1p[t], eb1 + t * 128, ew2p[t], eb2 + t * 64);
    cvt_bf4<<<(NN * LAT / 4 + 255) / 256, 256, 0, stream>>>((const float4*)recvb, (ushort4*)recvbf, NN * LAT / 4);
    node_mfma<<<1563, 256, 0, stream>>>(h, hbf, recvbf, gpad,
        nw1p[t], nb1 + t * 128, nw2p[t], nb2 + t * 64,
        lns + t * 64, lnb + t * 64);
  }

  decode_kernel<<<(NN * INF + 255) / 256, 256, 0, stream>>>(h, dw, db, (float*)d_out);
}

// Round 11
// 801.529 us; speedup vs baseline: 6.2328x; 1.0510x over previous
//
#include <hip/hip_runtime.h>

#define NN 50000
#define NE 800000
#define INF 7
#define GD 16
#define LAT 64
#define HID 128

typedef unsigned short u16;
typedef __attribute__((ext_vector_type(8))) __bf16 bf16x8;
typedef __attribute__((ext_vector_type(4))) float f32x4;

__device__ __forceinline__ float bf2f(u16 u) {
  union { unsigned int i; float f; } v; v.i = ((unsigned int)u) << 16; return v.f;
}
__device__ __forceinline__ u16 f2bf(float f) {
  union { float f; unsigned int i; } v; v.f = f;
  unsigned int x = v.i;
  return (u16)((x + 0x7fffu + ((x >> 16) & 1u)) >> 16);
}
// jax.nn.gelu approximate (tanh form), rewritten as x*sigmoid(2z) with v_rcp:
// 0.5x(1+tanh(z)) == x / (1 + exp(-2z)), z = 0.79788456(x + 0.044715 x^3).
// rcp is 1-ulp; exp overflow for very negative x gives rcp(inf)=0 -> correct limit.
__device__ __forceinline__ float gelu(float x) {
  float u = x * x;
  float p = fmaf(0.044715f * u, x, x);
  float e = __expf(-1.5957691216057308f * p);
  return x * __builtin_amdgcn_rcpf(e + 1.0f);
}

// ---- weight pre-pack: fragment-ordered bf16, K zero-padded to KC*32.
// out[((kc*NT+nt)*64 + lane)*8 + j] = bf16(W[kc*32+(lane>>4)*8+j][nt*16+(lane&15)])
__global__ void pack_w(const float* __restrict__ W, u16* __restrict__ out,
                       int K, int N, int KC) {
  int t = blockIdx.x * blockDim.x + threadIdx.x;
  int NT = N >> 4;
  if (t >= KC * NT * 64) return;
  int l = t & 63;
  int nt = (t >> 6) % NT;
  int kc = t / (64 * NT);
  int n = nt * 16 + (l & 15);
  int kbase = kc * 32 + (l >> 4) * 8;
  ushort4 lo, hi;
  u16 v[8];
#pragma unroll
  for (int j = 0; j < 8; ++j) {
    int k = kbase + j;
    v[j] = (k < K) ? f2bf(W[k * N + n]) : (u16)0;
  }
  lo.x = v[0]; lo.y = v[1]; lo.z = v[2]; lo.w = v[3];
  hi.x = v[4]; hi.y = v[5]; hi.z = v[6]; hi.w = v[7];
  ushort4* dst = (ushort4*)&out[(size_t)t * 8];
  dst[0] = lo; dst[1] = hi;
}

// g -> bf16, zero-padded to 32 entries (A-frags with q>=2 read zeros)
__global__ void g_pack(const float* __restrict__ g, u16* __restrict__ dst) {
  int i = threadIdx.x;
  if (i < 32) dst[i] = (i < GD) ? f2bf(g[i]) : (u16)0;
}

// fp32 -> bf16 bulk convert (recvbuf shadow)
__global__ void cvt_bf4(const float4* __restrict__ src, ushort4* __restrict__ dst, int n4) {
  int i = blockIdx.x * blockDim.x + threadIdx.x;
  if (i >= n4) return;
  float4 v = src[i];
  ushort4 o;
  o.x = f2bf(v.x); o.y = f2bf(v.y); o.z = f2bf(v.z); o.w = f2bf(v.w);
  dst[i] = o;
}

__global__ void embed_kernel(const float* __restrict__ nodes, const float* __restrict__ w,
                             const float* __restrict__ b, float* __restrict__ h,
                             u16* __restrict__ hbf) {
  int gid = blockIdx.x * blockDim.x + threadIdx.x;
  if (gid >= NN * LAT) return;
  int n = gid >> 6, j = gid & 63;
  float acc = b[j];
#pragma unroll
  for (int k = 0; k < INF; ++k)
    acc = fmaf(nodes[n * INF + k], w[k * LAT + j], acc);
  h[gid] = acc;
  hbf[gid] = f2bf(acc);
}

__global__ void zero_kernel(float4* __restrict__ p, int n4) {
  int i = blockIdx.x * blockDim.x + threadIdx.x;
  if (i < n4) p[i] = make_float4(0.f, 0.f, 0.f, 0.f);
}

// ---- MFMA edge MLP (round-7 structure: NO weight LDS staging -- staging W1 in
// LDS is empirically quarantined; r8/r9/r10 all failed with it, r6/r7 passed
// without). A-fragments (16B/lane) loaded directly from global.
// K layout FIRST: [s 64][r 64][g 16|pad] = 160 (KC=5)
//          else : [e 64][s 64][r 64][g 16|pad] = 224 (KC=7)
template <int KC, bool FIRST>
__launch_bounds__(256)
__global__ void edge_mfma(const u16* __restrict__ hbf, u16* __restrict__ ebuf,
                          float* __restrict__ recvbuf,
                          const int* __restrict__ snd, const int* __restrict__ rcv,
                          const u16* __restrict__ gpad,
                          const u16* __restrict__ w1p, const float* __restrict__ b1,
                          const u16* __restrict__ w2p, const float* __restrict__ b2) {
  __shared__ __align__(16) u16 hid[32 * 136];
  __shared__ __align__(16) u16 easm[32 * 64];
  __shared__ int rcvs[32];

  const int tid = threadIdx.x;
  const int lane = tid & 63;
  const int w = tid >> 6;
  const int l15 = lane & 15;
  const int q = lane >> 4;
  const int mr = w & 1;              // row-tile (16 rows) for both phases
  const int ntb1 = (w >> 1) * 4;     // phase-1 col-tiles (4 of 8)
  const int ntb2 = (w >> 1) * 2;     // phase-2 col-tiles (2 of 4)
  const int arow = mr * 16 + l15;

  float bb1[4], bb2[2];
#pragma unroll
  for (int i = 0; i < 4; ++i) bb1[i] = b1[(ntb1 + i) * 16 + l15];
#pragma unroll
  for (int i = 0; i < 2; ++i) bb2[i] = b2[(ntb2 + i) * 16 + l15];

  for (int tile = blockIdx.x; tile < NE / 32; tile += gridDim.x) {
    const int ebase = tile * 32;
    const int eg = ebase + arow;
    const int soff = snd[eg] * 64;
    const int roff = rcv[eg] * 64;
    if (tid < 32) rcvs[tid] = rcv[ebase + tid];

    // --- phase 1: hid = gelu(in @ W1 + b1)   [32 x 128]
    {
      f32x4 acc[4];
#pragma unroll
      for (int i = 0; i < 4; ++i) acc[i] = (f32x4){bb1[i], bb1[i], bb1[i], bb1[i]};
#pragma unroll
      for (int kc = 0; kc < KC; ++kc) {
        const u16* abase;
        if (FIRST) {
          abase = (kc < 2) ? &hbf[soff + kc * 32]
                : (kc < 4) ? &hbf[roff + (kc - 2) * 32]
                :            &gpad[0];
        } else {
          abase = (kc < 2) ? &ebuf[(size_t)eg * 64 + kc * 32]
                : (kc < 4) ? &hbf[soff + (kc - 2) * 32]
                : (kc < 6) ? &hbf[roff + (kc - 4) * 32]
                :            &gpad[0];
        }
        bf16x8 a = *(const bf16x8*)&abase[q * 8];
#pragma unroll
        for (int i = 0; i < 4; ++i) {
          bf16x8 b = *(const bf16x8*)&w1p[(size_t)((kc * 8 + ntb1 + i) * 64 + lane) * 8];
          acc[i] = __builtin_amdgcn_mfma_f32_16x16x32_bf16(a, b, acc[i], 0, 0, 0);
        }
      }
#pragma unroll
      for (int i = 0; i < 4; ++i) {
        const int col = (ntb1 + i) * 16 + l15;
#pragma unroll
        for (int r4 = 0; r4 < 4; ++r4) {
          const int row = mr * 16 + q * 4 + r4;
          hid[row * 136 + col] = f2bf(gelu(acc[i][r4]));
        }
      }
    }
    __syncthreads();
    // --- phase 2: out = hid @ W2 + b2   [32 x 64]; easm + atomics
    {
      f32x4 acc[2];
#pragma unroll
      for (int i = 0; i < 2; ++i) acc[i] = (f32x4){bb2[i], bb2[i], bb2[i], bb2[i]};
#pragma unroll
      for (int kc = 0; kc < 4; ++kc) {
        bf16x8 a = *(const bf16x8*)&hid[arow * 136 + kc * 32 + q * 8];
#pragma unroll
        for (int i = 0; i < 2; ++i) {
          bf16x8 b = *(const bf16x8*)&w2p[(size_t)((kc * 4 + ntb2 + i) * 64 + lane) * 8];
          acc[i] = __builtin_amdgcn_mfma_f32_16x16x32_bf16(a, b, acc[i], 0, 0, 0);
        }
      }
#pragma unroll
      for (int i = 0; i < 2; ++i) {
        const int col = (ntb2 + i) * 16 + l15;
#pragma unroll
        for (int r4 = 0; r4 < 4; ++r4) {
          const int row = mr * 16 + q * 4 + r4;
          const float v = acc[i][r4];
          easm[row * 64 + col] = f2bf(v);
          atomicAdd(&recvbuf[(size_t)rcvs[row] * 64 + col], v);
        }
      }
    }
    __syncthreads();
    // --- coalesced e_out write: 256 threads x 16B = 32 rows x 128B
    ((uint4*)&ebuf[(size_t)ebase * 64])[tid] = ((const uint4*)easm)[tid];
  }
}

// ---- MFMA node MLP + skip + LayerNorm (round-7 structure; W1 from global).
// 32 nodes/block. K layout: [h 64][recv 64][g 16|pad] = 160 (KC=5); phase2 K=128.
__launch_bounds__(256)
__global__ void node_mfma(float* __restrict__ h, u16* __restrict__ hbf,
                          const u16* __restrict__ recvbf,
                          const u16* __restrict__ gpad,
                          const u16* __restrict__ w1p, const float* __restrict__ b1,
                          const u16* __restrict__ w2p, const float* __restrict__ b2,
                          const float* __restrict__ lns, const float* __restrict__ lnb) {
  __shared__ __align__(16) u16 hid[32 * 136];
  __shared__ __align__(16) float outs[32 * 68];

  const int tid = threadIdx.x;
  const int lane = tid & 63;
  const int w = tid >> 6;
  const int l15 = lane & 15;
  const int q = lane >> 4;
  const int mr = w & 1;
  const int ntb1 = (w >> 1) * 4;
  const int ntb2 = (w >> 1) * 2;
  const int arow = mr * 16 + l15;

  float bb1[4], bb2[2];
#pragma unroll
  for (int i = 0; i < 4; ++i) bb1[i] = b1[(ntb1 + i) * 16 + l15];
#pragma unroll
  for (int i = 0; i < 2; ++i) bb2[i] = b2[(ntb2 + i) * 16 + l15];

  // LN per-thread constants: row nrow = tid>>3, cols jc..jc+7
  const int nrow = tid >> 3;
  const int jc = (tid & 7) * 8;
  float sc8[8], bi8[8];
#pragma unroll
  for (int k = 0; k < 8; ++k) { sc8[k] = lns[jc + k]; bi8[k] = lnb[jc + k]; }

  const int NT = (NN + 31) / 32;
  for (int tile = blockIdx.x; tile < NT; tile += gridDim.x) {
    const int nbase = tile * 32;
    const int na = min(nbase + arow, NN - 1) * 64;   // clamped A-row offset

    // --- phase 1
    {
      f32x4 acc[4];
#pragma unroll
      for (int i = 0; i < 4; ++i) acc[i] = (f32x4){bb1[i], bb1[i], bb1[i], bb1[i]};
#pragma unroll
      for (int kc = 0; kc < 5; ++kc) {
        const u16* abase = (kc < 2) ? &hbf[na + kc * 32]
                         : (kc < 4) ? &recvbf[na + (kc - 2) * 32]
                         :            &gpad[0];
        bf16x8 a = *(const bf16x8*)&abase[q * 8];
#pragma unroll
        for (int i = 0; i < 4; ++i) {
          bf16x8 b = *(const bf16x8*)&w1p[(size_t)((kc * 8 + ntb1 + i) * 64 + lane) * 8];
          acc[i] = __builtin_amdgcn_mfma_f32_16x16x32_bf16(a, b, acc[i], 0, 0, 0);
        }
      }
#pragma unroll
      for (int i = 0; i < 4; ++i) {
        const int col = (ntb1 + i) * 16 + l15;
#pragma unroll
        for (int r4 = 0; r4 < 4; ++r4) {
          const int row = mr * 16 + q * 4 + r4;
          hid[row * 136 + col] = f2bf(gelu(acc[i][r4]));
        }
      }
    }
    __syncthreads();
    // --- phase 2: upd = hid @ W2 + b2 -> outs (fp32 LDS)
    {
      f32x4 acc[2];
#pragma unroll
      for (int i = 0; i < 2; ++i) acc[i] = (f32x4){bb2[i], bb2[i], bb2[i], bb2[i]};
#pragma unroll
      for (int kc = 0; kc < 4; ++kc) {
        bf16x8 a = *(const bf16x8*)&hid[arow * 136 + kc * 32 + q * 8];
#pragma unroll
        for (int i = 0; i < 2; ++i) {
          bf16x8 b = *(const bf16x8*)&w2p[(size_t)((kc * 4 + ntb2 + i) * 64 + lane) * 8];
          acc[i] = __builtin_amdgcn_mfma_f32_16x16x32_bf16(a, b, acc[i], 0, 0, 0);
        }
      }
#pragma unroll
      for (int i = 0; i < 2; ++i) {
        const int col = (ntb2 + i) * 16 + l15;
#pragma unroll
        for (int r4 = 0; r4 < 4; ++r4) {
          const int row = mr * 16 + q * 4 + r4;
          outs[row * 68 + col] = acc[i][r4];
        }
      }
    }
    __syncthreads();
    // --- skip + LayerNorm: 8 threads per node row, 8 cols each
    {
      const int n = nbase + nrow;
      if (n < NN) {
        float x[8];
        float4 hv0 = *(const float4*)&h[n * 64 + jc];
        float4 hv1 = *(const float4*)&h[n * 64 + jc + 4];
        x[0] = hv0.x + outs[nrow * 68 + jc + 0];
        x[1] = hv0.y + outs[nrow * 68 + jc + 1];
        x[2] = hv0.z + outs[nrow * 68 + jc + 2];
        x[3] = hv0.w + outs[nrow * 68 + jc + 3];
        x[4] = hv1.x + outs[nrow * 68 + jc + 4];
        x[5] = hv1.y + outs[nrow * 68 + jc + 5];
        x[6] = hv1.z + outs[nrow * 68 + jc + 6];
        x[7] = hv1.w + outs[nrow * 68 + jc + 7];
        float s = 0.f, qq = 0.f;
#pragma unroll
        for (int k = 0; k < 8; ++k) { s += x[k]; qq += x[k] * x[k]; }
#pragma unroll
        for (int off = 1; off < 8; off <<= 1) {
          s += __shfl_xor(s, off);
          qq += __shfl_xor(qq, off);
        }
        float mean = s * (1.0f / 64.0f);
        float var = fmaxf(qq * (1.0f / 64.0f) - mean * mean, 0.0f);
        float rstd = rsqrtf(var + 1e-6f);
        float o[8];
        ushort4 ob0, ob1;
#pragma unroll
        for (int k = 0; k < 8; ++k) o[k] = (x[k] - mean) * rstd * sc8[k] + bi8[k];
        *(float4*)&h[n * 64 + jc]     = make_float4(o[0], o[1], o[2], o[3]);
        *(float4*)&h[n * 64 + jc + 4] = make_float4(o[4], o[5], o[6], o[7]);
        ob0.x = f2bf(o[0]); ob0.y = f2bf(o[1]); ob0.z = f2bf(o[2]); ob0.w = f2bf(o[3]);
        ob1.x = f2bf(o[4]); ob1.y = f2bf(o[5]); ob1.z = f2bf(o[6]); ob1.w = f2bf(o[7]);
        *(ushort4*)&hbf[n * 64 + jc]     = ob0;
        *(ushort4*)&hbf[n * 64 + jc + 4] = ob1;
      }
    }
    __syncthreads();   // protect hid/outs reuse next tile
  }
}

// Output dtype: float32 (reference returns fp32).
__global__ void decode_kernel(const float* __restrict__ h, const float* __restrict__ w,
                              const float* __restrict__ b, float* __restrict__ out) {
  int gid = blockIdx.x * blockDim.x + threadIdx.x;
  if (gid >= NN * INF) return;
  int n = gid / 7, f = gid % 7;
  float acc = b[f];
#pragma unroll
  for (int k = 0; k < LAT; ++k)
    acc = fmaf(h[n * 64 + k], w[k * 7 + f], acc);
  out[gid] = acc;
}

extern "C" void kernel_launch(void* const* d_in, const int* in_sizes, int n_in,
                              void* d_out, int out_size, void* d_ws, size_t ws_size,
                              hipStream_t stream) {
  const float* nodes = (const float*)d_in[0];
  const int* senders = (const int*)d_in[1];
  const int* recvrs  = (const int*)d_in[2];
  const float* g     = (const float*)d_in[3];
  const float* emb_w = (const float*)d_in[4];
  const float* emb_b = (const float*)d_in[5];
  const float* ew1f  = (const float*)d_in[6];
  const float* ew1r  = (const float*)d_in[7];
  const float* eb1   = (const float*)d_in[8];
  const float* ew2   = (const float*)d_in[9];
  const float* eb2   = (const float*)d_in[10];
  const float* nw1   = (const float*)d_in[11];
  const float* nb1   = (const float*)d_in[12];
  const float* nw2   = (const float*)d_in[13];
  const float* nb2   = (const float*)d_in[14];
  const float* lns   = (const float*)d_in[15];
  const float* lnb   = (const float*)d_in[16];
  const float* dw    = (const float*)d_in[17];
  const float* db    = (const float*)d_in[18];

  char* cur = (char*)d_ws;
  float* h      = (float*)cur;  cur += (size_t)NN * LAT * 4;        // 12.8 MB
  float* recvb  = (float*)cur;  cur += (size_t)NN * LAT * 4;        // 12.8 MB
  u16*   ebuf   = (u16*)cur;    cur += (size_t)NE * LAT * 2;        // 102.4 MB
  u16*   hbf    = (u16*)cur;    cur += (size_t)NN * LAT * 2;        // 6.4 MB
  u16*   recvbf = (u16*)cur;    cur += (size_t)NN * LAT * 2;        // 6.4 MB
  u16*   ew1p[3]; for (int t = 0; t < 3; ++t) { ew1p[t] = (u16*)cur; cur += 7 * 8 * 64 * 8 * 2; }
  u16*   ew2p[3]; for (int t = 0; t < 3; ++t) { ew2p[t] = (u16*)cur; cur += 4 * 4 * 64 * 8 * 2; }
  u16*   nw1p[3]; for (int t = 0; t < 3; ++t) { nw1p[t] = (u16*)cur; cur += 5 * 8 * 64 * 8 * 2; }
  u16*   nw2p[3]; for (int t = 0; t < 3; ++t) { nw2p[t] = (u16*)cur; cur += 4 * 4 * 64 * 8 * 2; }
  u16*   gpad   = (u16*)cur;    cur += 64;

  // pre-pack weights (per launch; graph-capture safe)
  pack_w<<<(5 * 8 * 64 + 255) / 256, 256, 0, stream>>>(ew1f, ew1p[0], 144, 128, 5);
  pack_w<<<(7 * 8 * 64 + 255) / 256, 256, 0, stream>>>(ew1r, ew1p[1], 208, 128, 7);
  pack_w<<<(7 * 8 * 64 + 255) / 256, 256, 0, stream>>>(ew1r + (size_t)208 * 128, ew1p[2], 208, 128, 7);
  for (int t = 0; t < 3; ++t) {
    pack_w<<<(4 * 4 * 64 + 255) / 256, 256, 0, stream>>>(ew2 + (size_t)t * 128 * 64, ew2p[t], 128, 64, 4);
    pack_w<<<(5 * 8 * 64 + 255) / 256, 256, 0, stream>>>(nw1 + (size_t)t * 144 * 128, nw1p[t], 144, 128, 5);
    pack_w<<<(4 * 4 * 64 + 255) / 256, 256, 0, stream>>>(nw2 + (size_t)t * 128 * 64, nw2p[t], 128, 64, 4);
  }
  g_pack<<<1, 64, 0, stream>>>(g, gpad);

  embed_kernel<<<(NN * LAT + 255) / 256, 256, 0, stream>>>(nodes, emb_w, emb_b, h, hbf);

  for (int t = 0; t < 3; ++t) {
    zero_kernel<<<(NN * LAT / 4 + 255) / 256, 256, 0, stream>>>((float4*)recvb, NN * LAT / 4);
    if (t == 0)
      edge_mfma<5, true><<<2048, 256, 0, stream>>>(hbf, ebuf, recvb,
          senders, recvrs, gpad, ew1p[0], eb1, ew2p[0], eb2);
    else
      edge_mfma<7, false><<<2048, 256, 0, stream>>>(hbf, ebuf, recvb,
          senders, recvrs, gpad, ew1p[t], eb1 + t * 128, ew2p[t], eb2 + t * 64);
    cvt_bf4<<<(NN * LAT / 4 + 255) / 256, 256, 0, stream>>>((const float4*)recvb, (ushort4*)recvbf, NN * LAT / 4);
    node_mfma<<<1563, 256, 0, stream>>>(h, hbf, recvbf, gpad,
        nw1p[t], nb1 + t * 128, nw2p[t], nb2 + t * 64,
        lns + t * 64, lnb + t * 64);
  }

  decode_kernel<<<(NN * INF + 255) / 256, 256, 0, stream>>>(h, dw, db, (float*)d_out);
}